// Round 6
// baseline (359.138 us; speedup 1.0000x reference)
//
#include <hip/hip_runtime.h>
#include <hip/hip_fp16.h>

// SimpleAttention on MI355X (gfx950), f16 MFMA path with fp32 accum.
// Pipeline: cast(x,wqkv,wout) -> QKV GEMM -> causal flash attn -> out GEMM.
// Q is pre-scaled by 0.125*log2(e) so attn softmax runs in exp2 domain.
// R5: attn regrid 512->1024 blocks (16-row waves) to fix 11% occupancy;
//     out-GEMM BM 128->64 (512 blocks, was 256).

typedef _Float16 half8 __attribute__((ext_vector_type(8)));
typedef _Float16 half4 __attribute__((ext_vector_type(4)));
typedef float f32x4 __attribute__((ext_vector_type(4)));

typedef const __attribute__((address_space(1))) void gvoid_t;
typedef __attribute__((address_space(3))) void lvoid_t;

#define LOG2E 1.4426950408889634f
#define QSCALE (0.125f * LOG2E)

// ---------------- fused fp32 -> fp16 cast, 8 elems/thread ----------------
__global__ void cast_all_f16(const float* __restrict__ x, const float* __restrict__ wq,
                             const float* __restrict__ wo, _Float16* __restrict__ xh,
                             _Float16* __restrict__ wqh, _Float16* __restrict__ woh) {
  int i = blockIdx.x * blockDim.x + threadIdx.x;
  const float* src;
  _Float16* dst;
  int off;
  if (i < 524288) { src = x; dst = xh; off = i; }
  else if (i < 917504) { src = wq; dst = wqh; off = i - 524288; }
  else { src = wo; dst = woh; off = i - 917504; }
  const float4* p = reinterpret_cast<const float4*>(src) + (size_t)off * 2;
  float4 a = p[0], b = p[1];
  half8 h;
  h[0] = (_Float16)a.x; h[1] = (_Float16)a.y; h[2] = (_Float16)a.z; h[3] = (_Float16)a.w;
  h[4] = (_Float16)b.x; h[5] = (_Float16)b.y; h[6] = (_Float16)b.z; h[7] = (_Float16)b.w;
  reinterpret_cast<half8*>(dst)[off] = h;
}

// ---------------- QKV GEMM: C[M,N] = A[M,K] * B[N,K]^T, K=1024 ----------------
// 128x128 tile, BK=32, 4 waves (each 64x64 = 4x4 frags of 16x16x32 f16 MFMA).
// Scatter into Q[b,h,s,d] (pre-scaled), K[b,h,s,d], Vt[b,h,d,s] (f16)
__global__ __launch_bounds__(256) void gemm_qkv(
    const _Float16* __restrict__ A, const _Float16* __restrict__ B,
    _Float16* __restrict__ Qo, _Float16* __restrict__ Ko, _Float16* __restrict__ Vto)
{
  __shared__ __align__(16) _Float16 As[128 * 32];
  __shared__ __align__(16) _Float16 Bs[128 * 32];
  const int tid = threadIdx.x;
  const int lane = tid & 63;
  const int w = tid >> 6;
  const int lr = lane & 15, hi = lane >> 4;
  const int wr = w >> 1, wc = w & 1;
  const int gm = blockIdx.y, gn = blockIdx.x;
  const _Float16* gA = A + (size_t)gm * 128 * 1024;
  const _Float16* gB = B + (size_t)gn * 128 * 1024;
  f32x4 acc[4][4] = {};

#define STAGE2(gp, sp)                                                                  \
  { _Pragma("unroll") for (int i_ = 0; i_ < 2; ++i_) {                                  \
      int c_ = i_ * 256 + tid; int r_ = c_ >> 2; int ko_ = (c_ & 3) * 8;                \
      __builtin_amdgcn_global_load_lds((gvoid_t*)((gp) + r_ * 1024 + ko_),              \
                                       (lvoid_t*)((sp) + c_ * 8), 16, 0, 0);            \
    } }

  STAGE2(gA, As)
  STAGE2(gB, Bs)
  for (int ks = 0;; ++ks) {
    __syncthreads();
    half8 af[4], bf[4];
#pragma unroll
    for (int mi = 0; mi < 4; ++mi)
      af[mi] = *reinterpret_cast<const half8*>(As + (wr * 64 + mi * 16 + lr) * 32 + hi * 8);
#pragma unroll
    for (int ni = 0; ni < 4; ++ni)
      bf[ni] = *reinterpret_cast<const half8*>(Bs + (wc * 64 + ni * 16 + lr) * 32 + hi * 8);
#pragma unroll
    for (int mi = 0; mi < 4; ++mi)
#pragma unroll
      for (int ni = 0; ni < 4; ++ni)
        acc[mi][ni] = __builtin_amdgcn_mfma_f32_16x16x32_f16(af[mi], bf[ni], acc[mi][ni], 0, 0, 0);
    if (ks == 31) break;
    __syncthreads();
    STAGE2(gA + (ks + 1) * 32, As)
    STAGE2(gB + (ks + 1) * 32, Bs)
  }

  const int row0 = gm * 128 + wr * 64;
  const int col0 = gn * 128 + wc * 64;
#pragma unroll
  for (int ni = 0; ni < 4; ++ni) {
    int col = col0 + ni * 16 + lr;          // 0..3071
    int t = col >> 10, h = (col >> 6) & 15, d = col & 63;
#pragma unroll
    for (int mi = 0; mi < 4; ++mi) {
      int row = row0 + mi * 16 + hi * 4;    // j=0 row; j stays within same b (row%4==0)
      int b = row >> 11, s = row & 2047;
      if (t == 2) {
        half4 pk = { (_Float16)acc[mi][ni][0], (_Float16)acc[mi][ni][1],
                     (_Float16)acc[mi][ni][2], (_Float16)acc[mi][ni][3] };
        *reinterpret_cast<half4*>(Vto + ((size_t)(b * 16 + h) * 64 + d) * 2048 + s) = pk;
      } else if (t == 0) {
#pragma unroll
        for (int j = 0; j < 4; ++j)
          Qo[(size_t)((b * 16 + h) * 2048 + s + j) * 64 + d] =
              (_Float16)(acc[mi][ni][j] * QSCALE);
      } else {
#pragma unroll
        for (int j = 0; j < 4; ++j)
          Ko[(size_t)((b * 16 + h) * 2048 + s + j) * 64 + d] = (_Float16)acc[mi][ni][j];
      }
    }
  }
}

// ---------------- out GEMM: Co[4096,1024] = A[4096,K]*B[1024,K]^T ----------------
// BM=64 x BN=128 tile, 4 waves each 64x32 (acc[4][2]); grid (8, 64) = 512 blocks.
__global__ __launch_bounds__(256) void gemm_out64(
    const _Float16* __restrict__ A, const _Float16* __restrict__ B,
    float* __restrict__ Co)
{
  __shared__ __align__(16) _Float16 As[64 * 32];
  __shared__ __align__(16) _Float16 Bs[128 * 32];
  const int tid = threadIdx.x;
  const int lane = tid & 63;
  const int w = tid >> 6;
  const int lr = lane & 15, hi = lane >> 4;
  const int gm = blockIdx.y, gn = blockIdx.x;
  const _Float16* gA = A + (size_t)gm * 64 * 1024;
  const _Float16* gB = B + (size_t)gn * 128 * 1024;
  f32x4 acc[4][2] = {};

#define STAGEA(gp)                                                                      \
  { int r_ = tid >> 2; int ko_ = (tid & 3) * 8;                                         \
    __builtin_amdgcn_global_load_lds((gvoid_t*)((gp) + r_ * 1024 + ko_),                \
                                     (lvoid_t*)(As + tid * 8), 16, 0, 0); }

  STAGEA(gA)
  STAGE2(gB, Bs)
  for (int ks = 0;; ++ks) {
    __syncthreads();
    half8 af[4], bf[2];
#pragma unroll
    for (int mi = 0; mi < 4; ++mi)
      af[mi] = *reinterpret_cast<const half8*>(As + (mi * 16 + lr) * 32 + hi * 8);
#pragma unroll
    for (int ni = 0; ni < 2; ++ni)
      bf[ni] = *reinterpret_cast<const half8*>(Bs + (w * 32 + ni * 16 + lr) * 32 + hi * 8);
#pragma unroll
    for (int mi = 0; mi < 4; ++mi)
#pragma unroll
      for (int ni = 0; ni < 2; ++ni)
        acc[mi][ni] = __builtin_amdgcn_mfma_f32_16x16x32_f16(af[mi], bf[ni], acc[mi][ni], 0, 0, 0);
    if (ks == 31) break;
    __syncthreads();
    STAGEA(gA + (ks + 1) * 32)
    STAGE2(gB + (ks + 1) * 32, Bs)
  }
#undef STAGEA
#undef STAGE2

#pragma unroll
  for (int mi = 0; mi < 4; ++mi)
#pragma unroll
    for (int j = 0; j < 4; ++j) {
      int row = gm * 64 + mi * 16 + hi * 4 + j;
#pragma unroll
      for (int ni = 0; ni < 2; ++ni) {
        int col = gn * 128 + w * 32 + ni * 16 + lr;
        Co[(size_t)row * 1024 + col] = acc[mi][ni][j];
      }
    }
}

// ---------------- causal flash attention ----------------
// grid (32, 32): x = q-tile of 64 rows (descending work order), y = b*NH+h.
// 4 waves/block, each owns 16 q-rows; 64-key tiles; online softmax (exp2 domain).
// All waves in a block have identical trip count nkt = qt+1; no barriers needed
// (per-wave P buffer). K/V frag loads issue at tile top (latency under softmax).
__global__ __launch_bounds__(256, 4) void attn_f16(
    const _Float16* __restrict__ Qg, const _Float16* __restrict__ Kg,
    const _Float16* __restrict__ Vtg, _Float16* __restrict__ AO)
{
  const int bh = blockIdx.y;
  const int qt = 31 - blockIdx.x;  // big tiles launch first
  const int tid = threadIdx.x;
  const int w = tid >> 6, lane = tid & 63;
  const int lr = lane & 15, hi = lane >> 4;
  const _Float16* Qh = Qg + (size_t)bh * 2048 * 64;
  const _Float16* Kh = Kg + (size_t)bh * 2048 * 64;
  const _Float16* Vh = Vtg + (size_t)bh * 64 * 2048;  // [d][s]
  const int qg0 = qt * 64 + w * 16;
  __shared__ __align__(16) _Float16 Plds[4][16][88];  // per-wave P, stride 88
  _Float16(*P)[88] = Plds[w];

  // Q fragments: 16 rows x 64 d per wave (pre-scaled by QSCALE)
  half8 qf[2];
#pragma unroll
  for (int kk = 0; kk < 2; ++kk)
    qf[kk] = *reinterpret_cast<const half8*>(
        Qh + (size_t)(qg0 + lr) * 64 + kk * 32 + hi * 8);

  f32x4 accO[4] = {};
  f32x4 mrun, lrun;
#pragma unroll
  for (int j = 0; j < 4; ++j) { mrun[j] = -1e30f; lrun[j] = 0.f; }

  const int nkt = (qg0 >> 6) + 1;  // == qt+1 for every wave in the block
  for (int kt = 0; kt < nkt; ++kt) {
    const int k0 = kt * 64;
    const bool diag = (k0 + 63 > qg0);
    // ---- all global loads for this tile issue together (K frags + V frags) ----
    half8 kf[4][2];
#pragma unroll
    for (int ni = 0; ni < 4; ++ni)
#pragma unroll
      for (int kk = 0; kk < 2; ++kk)
        kf[ni][kk] = *reinterpret_cast<const half8*>(
            Kh + (size_t)(k0 + ni * 16 + lr) * 64 + kk * 32 + hi * 8);
    half8 vf[2][4];
#pragma unroll
    for (int kk = 0; kk < 2; ++kk)
#pragma unroll
      for (int nd = 0; nd < 4; ++nd)
        vf[kk][nd] = *reinterpret_cast<const half8*>(
            Vh + (size_t)(nd * 16 + lr) * 2048 + k0 + kk * 32 + hi * 8);
    // ---- scores2 = (Q*QSCALE) K^T (log2-domain) ----
    f32x4 accS[4] = {};
#pragma unroll
    for (int ni = 0; ni < 4; ++ni)
#pragma unroll
      for (int kk = 0; kk < 2; ++kk)
        accS[ni] = __builtin_amdgcn_mfma_f32_16x16x32_f16(qf[kk], kf[ni][kk], accS[ni], 0, 0, 0);
    // ---- causal mask ----
    if (diag) {
#pragma unroll
      for (int ni = 0; ni < 4; ++ni)
#pragma unroll
        for (int j = 0; j < 4; ++j) {
          int colg = k0 + ni * 16 + lr;
          int rowg = qg0 + hi * 4 + j;
          if (colg > rowg) accS[ni][j] = -1e30f;
        }
    }
    // ---- online softmax, exp2 domain ----
    f32x4 rmax = accS[0];
#pragma unroll
    for (int ni = 1; ni < 4; ++ni)
#pragma unroll
      for (int j = 0; j < 4; ++j) rmax[j] = fmaxf(rmax[j], accS[ni][j]);
#pragma unroll
    for (int d = 1; d < 16; d <<= 1)
#pragma unroll
      for (int j = 0; j < 4; ++j) rmax[j] = fmaxf(rmax[j], __shfl_xor(rmax[j], d));
    f32x4 mnew, corr;
#pragma unroll
    for (int j = 0; j < 4; ++j) {
      mnew[j] = fmaxf(mrun[j], rmax[j]);
      corr[j] = exp2f(mrun[j] - mnew[j]);
      mrun[j] = mnew[j];
    }
    f32x4 rsum = {};
#pragma unroll
    for (int ni = 0; ni < 4; ++ni)
#pragma unroll
      for (int j = 0; j < 4; ++j) {
        float pv = exp2f(accS[ni][j] - mnew[j]);
        rsum[j] += pv;
        P[hi * 4 + j][ni * 16 + lr] = (_Float16)pv;  // C-layout -> LDS
      }
#pragma unroll
    for (int d = 1; d < 16; d <<= 1)
#pragma unroll
      for (int j = 0; j < 4; ++j) rsum[j] += __shfl_xor(rsum[j], d);
#pragma unroll
    for (int j = 0; j < 4; ++j) lrun[j] = lrun[j] * corr[j] + rsum[j];
#pragma unroll
    for (int nd = 0; nd < 4; ++nd)
#pragma unroll
      for (int j = 0; j < 4; ++j) accO[nd][j] *= corr[j];
    // ---- PV: O += P @ V (P re-read in A-frag layout; V already in registers) ----
#pragma unroll
    for (int kk = 0; kk < 2; ++kk) {
      half8 pa = *reinterpret_cast<const half8*>(&P[lr][kk * 32 + hi * 8]);
#pragma unroll
      for (int nd = 0; nd < 4; ++nd)
        accO[nd] = __builtin_amdgcn_mfma_f32_16x16x32_f16(pa, vf[kk][nd], accO[nd], 0, 0, 0);
    }
  }
  // ---- epilogue: AO[b, s, h*64+d] = O / l ----
  const int b = bh >> 4, h = bh & 15;
  f32x4 inv;
#pragma unroll
  for (int j = 0; j < 4; ++j) inv[j] = 1.0f / lrun[j];
#pragma unroll
  for (int nd = 0; nd < 4; ++nd)
#pragma unroll
    for (int j = 0; j < 4; ++j) {
      int s = qg0 + hi * 4 + j;
      int d = nd * 16 + lr;
      AO[(size_t)(b * 2048 + s) * 1024 + h * 64 + d] = (_Float16)(accO[nd][j] * inv[j]);
    }
}

extern "C" void kernel_launch(void* const* d_in, const int* in_sizes, int n_in,
                              void* d_out, int out_size, void* d_ws, size_t ws_size,
                              hipStream_t stream) {
  const float* x = (const float*)d_in[0];      // [2,2048,1024]
  const float* wqkv = (const float*)d_in[1];   // [3072,1024]
  const float* wout = (const float*)d_in[2];   // [1024,1024]
  float* out = (float*)d_out;                  // [2,2048,1024] fp32
  char* ws = (char*)d_ws;
  _Float16* xh  = (_Float16*)(ws + (size_t)0);          // 8 MB
  _Float16* wqh = (_Float16*)(ws + ((size_t)8 << 20));  // 6 MB
  _Float16* woh = (_Float16*)(ws + ((size_t)14 << 20)); // 2 MB
  _Float16* Qb  = (_Float16*)(ws + ((size_t)16 << 20)); // 8 MB [b,h,s,d] pre-scaled
  _Float16* Kb  = (_Float16*)(ws + ((size_t)24 << 20)); // 8 MB [b,h,s,d]
  _Float16* Vtb = (_Float16*)(ws + ((size_t)32 << 20)); // 8 MB [b,h,d,s]
  _Float16* AOb = (_Float16*)(ws + ((size_t)40 << 20)); // 8 MB [b,s,h*64+d]

  cast_all_f16<<<dim3(4096), 256, 0, stream>>>(x, wqkv, wout, xh, wqh, woh);
  gemm_qkv<<<dim3(24, 32), 256, 0, stream>>>(xh, wqh, Qb, Kb, Vtb);
  attn_f16<<<dim3(32, 32), 256, 0, stream>>>(Qb, Kb, Vtb, AOb);
  gemm_out64<<<dim3(8, 64), 256, 0, stream>>>(AOb, woh, out);
}

// Round 7
// 205.119 us; speedup vs baseline: 1.7509x; 1.7509x over previous
//
#include <hip/hip_runtime.h>
#include <hip/hip_fp16.h>

// SimpleAttention on MI355X (gfx950), f16 MFMA path with fp32 accum.
// Pipeline: cast(x,wqkv,wout) -> QKV GEMM -> causal flash attn -> out GEMM.
// R7 attn: paired causal q-tiles (uniform 33 key-tiles/block), block-coop
// double-buffered K/V LDS staging (global_load_lds + counted vmcnt, XOR-swizzled
// via pre-swizzled global source), XCD-chunked block swizzle for L2 locality.

typedef _Float16 half8 __attribute__((ext_vector_type(8)));
typedef _Float16 half4 __attribute__((ext_vector_type(4)));
typedef float f32x4 __attribute__((ext_vector_type(4)));

typedef const __attribute__((address_space(1))) void gvoid_t;
typedef __attribute__((address_space(3))) void lvoid_t;

#define LOG2E 1.4426950408889634f
#define QSCALE (0.125f * LOG2E)

// ---------------- fused fp32 -> fp16 cast, 8 elems/thread ----------------
__global__ void cast_all_f16(const float* __restrict__ x, const float* __restrict__ wq,
                             const float* __restrict__ wo, _Float16* __restrict__ xh,
                             _Float16* __restrict__ wqh, _Float16* __restrict__ woh) {
  int i = blockIdx.x * blockDim.x + threadIdx.x;
  const float* src;
  _Float16* dst;
  int off;
  if (i < 524288) { src = x; dst = xh; off = i; }
  else if (i < 917504) { src = wq; dst = wqh; off = i - 524288; }
  else { src = wo; dst = woh; off = i - 917504; }
  const float4* p = reinterpret_cast<const float4*>(src) + (size_t)off * 2;
  float4 a = p[0], b = p[1];
  half8 h;
  h[0] = (_Float16)a.x; h[1] = (_Float16)a.y; h[2] = (_Float16)a.z; h[3] = (_Float16)a.w;
  h[4] = (_Float16)b.x; h[5] = (_Float16)b.y; h[6] = (_Float16)b.z; h[7] = (_Float16)b.w;
  reinterpret_cast<half8*>(dst)[off] = h;
}

// ---------------- QKV GEMM: C[M,N] = A[M,K] * B[N,K]^T, K=1024 ----------------
__global__ __launch_bounds__(256) void gemm_qkv(
    const _Float16* __restrict__ A, const _Float16* __restrict__ B,
    _Float16* __restrict__ Qo, _Float16* __restrict__ Ko, _Float16* __restrict__ Vto)
{
  __shared__ __align__(16) _Float16 As[128 * 32];
  __shared__ __align__(16) _Float16 Bs[128 * 32];
  const int tid = threadIdx.x;
  const int lane = tid & 63;
  const int w = tid >> 6;
  const int lr = lane & 15, hi = lane >> 4;
  const int wr = w >> 1, wc = w & 1;
  const int gm = blockIdx.y, gn = blockIdx.x;
  const _Float16* gA = A + (size_t)gm * 128 * 1024;
  const _Float16* gB = B + (size_t)gn * 128 * 1024;
  f32x4 acc[4][4] = {};

#define STAGE2(gp, sp)                                                                  \
  { _Pragma("unroll") for (int i_ = 0; i_ < 2; ++i_) {                                  \
      int c_ = i_ * 256 + tid; int r_ = c_ >> 2; int ko_ = (c_ & 3) * 8;                \
      __builtin_amdgcn_global_load_lds((gvoid_t*)((gp) + r_ * 1024 + ko_),              \
                                       (lvoid_t*)((sp) + c_ * 8), 16, 0, 0);            \
    } }

  STAGE2(gA, As)
  STAGE2(gB, Bs)
  for (int ks = 0;; ++ks) {
    __syncthreads();
    half8 af[4], bf[4];
#pragma unroll
    for (int mi = 0; mi < 4; ++mi)
      af[mi] = *reinterpret_cast<const half8*>(As + (wr * 64 + mi * 16 + lr) * 32 + hi * 8);
#pragma unroll
    for (int ni = 0; ni < 4; ++ni)
      bf[ni] = *reinterpret_cast<const half8*>(Bs + (wc * 64 + ni * 16 + lr) * 32 + hi * 8);
#pragma unroll
    for (int mi = 0; mi < 4; ++mi)
#pragma unroll
      for (int ni = 0; ni < 4; ++ni)
        acc[mi][ni] = __builtin_amdgcn_mfma_f32_16x16x32_f16(af[mi], bf[ni], acc[mi][ni], 0, 0, 0);
    if (ks == 31) break;
    __syncthreads();
    STAGE2(gA + (ks + 1) * 32, As)
    STAGE2(gB + (ks + 1) * 32, Bs)
  }

  const int row0 = gm * 128 + wr * 64;
  const int col0 = gn * 128 + wc * 64;
#pragma unroll
  for (int ni = 0; ni < 4; ++ni) {
    int col = col0 + ni * 16 + lr;          // 0..3071
    int t = col >> 10, h = (col >> 6) & 15, d = col & 63;
#pragma unroll
    for (int mi = 0; mi < 4; ++mi) {
      int row = row0 + mi * 16 + hi * 4;    // j=0 row; j stays within same b
      int b = row >> 11, s = row & 2047;
      if (t == 2) {
        half4 pk = { (_Float16)acc[mi][ni][0], (_Float16)acc[mi][ni][1],
                     (_Float16)acc[mi][ni][2], (_Float16)acc[mi][ni][3] };
        *reinterpret_cast<half4*>(Vto + ((size_t)(b * 16 + h) * 64 + d) * 2048 + s) = pk;
      } else if (t == 0) {
#pragma unroll
        for (int j = 0; j < 4; ++j)
          Qo[(size_t)((b * 16 + h) * 2048 + s + j) * 64 + d] =
              (_Float16)(acc[mi][ni][j] * QSCALE);
      } else {
#pragma unroll
        for (int j = 0; j < 4; ++j)
          Ko[(size_t)((b * 16 + h) * 2048 + s + j) * 64 + d] = (_Float16)acc[mi][ni][j];
      }
    }
  }
}

// ---------------- out GEMM: Co[4096,1024] = A[4096,K]*B[1024,K]^T ----------------
__global__ __launch_bounds__(256) void gemm_out64(
    const _Float16* __restrict__ A, const _Float16* __restrict__ B,
    float* __restrict__ Co)
{
  __shared__ __align__(16) _Float16 As[64 * 32];
  __shared__ __align__(16) _Float16 Bs[128 * 32];
  const int tid = threadIdx.x;
  const int lane = tid & 63;
  const int w = tid >> 6;
  const int lr = lane & 15, hi = lane >> 4;
  const int gm = blockIdx.y, gn = blockIdx.x;
  const _Float16* gA = A + (size_t)gm * 64 * 1024;
  const _Float16* gB = B + (size_t)gn * 128 * 1024;
  f32x4 acc[4][2] = {};

#define STAGEA(gp)                                                                      \
  { int r_ = tid >> 2; int ko_ = (tid & 3) * 8;                                         \
    __builtin_amdgcn_global_load_lds((gvoid_t*)((gp) + r_ * 1024 + ko_),                \
                                     (lvoid_t*)(As + tid * 8), 16, 0, 0); }

  STAGEA(gA)
  STAGE2(gB, Bs)
  for (int ks = 0;; ++ks) {
    __syncthreads();
    half8 af[4], bf[2];
#pragma unroll
    for (int mi = 0; mi < 4; ++mi)
      af[mi] = *reinterpret_cast<const half8*>(As + (mi * 16 + lr) * 32 + hi * 8);
#pragma unroll
    for (int ni = 0; ni < 2; ++ni)
      bf[ni] = *reinterpret_cast<const half8*>(Bs + (w * 32 + ni * 16 + lr) * 32 + hi * 8);
#pragma unroll
    for (int mi = 0; mi < 4; ++mi)
#pragma unroll
      for (int ni = 0; ni < 2; ++ni)
        acc[mi][ni] = __builtin_amdgcn_mfma_f32_16x16x32_f16(af[mi], bf[ni], acc[mi][ni], 0, 0, 0);
    if (ks == 31) break;
    __syncthreads();
    STAGEA(gA + (ks + 1) * 32)
    STAGE2(gB + (ks + 1) * 32, Bs)
  }
#undef STAGEA
#undef STAGE2

#pragma unroll
  for (int mi = 0; mi < 4; ++mi)
#pragma unroll
    for (int j = 0; j < 4; ++j) {
      int row = gm * 64 + mi * 16 + hi * 4 + j;
#pragma unroll
      for (int ni = 0; ni < 2; ++ni) {
        int col = gn * 128 + w * 32 + ni * 16 + lr;
        Co[(size_t)row * 1024 + col] = acc[mi][ni][j];
      }
    }
}

// ---------------- causal flash attention (R7) ----------------
// 512 blocks (1-D). Block -> (pair p, bh) via XCD-chunked swizzle (4 bh / XCD).
// Block processes q-tile p (64 rows) then q-tile 31-p: uniform 33 key-tiles total.
// 4 waves x 16 q-rows; K/V staged to LDS (double-buffered, swizzled) per tile.
__global__ __launch_bounds__(256, 2) void attn_f16(
    const _Float16* __restrict__ Qg, const _Float16* __restrict__ Kg,
    const _Float16* __restrict__ Vtg, _Float16* __restrict__ AO)
{
  const int bid = blockIdx.x;
  const int virt = ((bid & 7) << 6) | (bid >> 3);  // 512 = 8 XCDs x 64-chunk, bijective
  const int p = virt & 15;
  const int bh = virt >> 4;
  const int tid = threadIdx.x;
  const int w = tid >> 6, lane = tid & 63;
  const int lr = lane & 15, hi = lane >> 4;
  const _Float16* Qh = Qg + (size_t)bh * 2048 * 64;
  const _Float16* Kh = Kg + (size_t)bh * 2048 * 64;
  const _Float16* Vh = Vtg + (size_t)bh * 64 * 2048;  // [d][s]
  const int b = bh >> 4, h = bh & 15;

  __shared__ __align__(16) _Float16 Kst[2][64 * 64];  // 8KB x2, XOR-swizzled slots
  __shared__ __align__(16) _Float16 Vst[2][64 * 64];  // 8KB x2
  __shared__ __align__(16) _Float16 Plds[4][16][88];  // per-wave P
  _Float16(*P)[88] = Plds[w];

  // Stage one 64-key tile of K and V into LDS buf. Source is pre-swizzled so a
  // linear global_load_lds dest + swizzled ds_read = conflict-free (rule 21).
  auto STAGE = [&](int buf, int kt) {
    const int k0 = kt * 64;
#pragma unroll
    for (int i = 0; i < 2; ++i) {
      int f = i * 256 + tid, r = f >> 3, s = f & 7, ss = s ^ (r & 7);
      __builtin_amdgcn_global_load_lds((gvoid_t*)(Kh + (size_t)(k0 + r) * 64 + ss * 8),
                                       (lvoid_t*)(&Kst[buf][f * 8]), 16, 0, 0);
    }
#pragma unroll
    for (int i = 0; i < 2; ++i) {
      int f = i * 256 + tid, r = f >> 3, s = f & 7, ss = s ^ (r & 7);
      __builtin_amdgcn_global_load_lds((gvoid_t*)(Vh + (size_t)r * 2048 + k0 + ss * 8),
                                       (lvoid_t*)(&Vst[buf][f * 8]), 16, 0, 0);
    }
  };

  auto PHASE = [&](int q0, int nkt) {
    const int qg0 = q0 + w * 16;
    half8 qf[2];
#pragma unroll
    for (int kk = 0; kk < 2; ++kk)
      qf[kk] = *reinterpret_cast<const half8*>(Qh + (size_t)(qg0 + lr) * 64 + kk * 32 + hi * 8);
    f32x4 accO[4] = {};
    f32x4 mrun, lrun;
#pragma unroll
    for (int j = 0; j < 4; ++j) { mrun[j] = -1e30f; lrun[j] = 0.f; }

    asm volatile("s_barrier" ::: "memory");  // all waves done with prev phase's bufs
    STAGE(0, 0);
    for (int kt = 0; kt < nkt; ++kt) {
      const int k0 = kt * 64;
      const int cur = kt & 1;
      if (kt + 1 < nkt) {
        STAGE(cur ^ 1, kt + 1);
        asm volatile("s_waitcnt vmcnt(4)" ::: "memory");  // prior stage (4 loads) done
      } else {
        asm volatile("s_waitcnt vmcnt(0)" ::: "memory");
      }
      __builtin_amdgcn_sched_barrier(0);
      asm volatile("s_barrier" ::: "memory");  // buf[cur] ready for all waves
      // ---- fragments from LDS (swizzled read) ----
      half8 kf[4][2], vf[2][4];
#pragma unroll
      for (int ni = 0; ni < 4; ++ni)
#pragma unroll
        for (int kk = 0; kk < 2; ++kk)
          kf[ni][kk] = *reinterpret_cast<const half8*>(
              &Kst[cur][(ni * 16 + lr) * 64 + ((kk * 4 + hi) ^ (lr & 7)) * 8]);
#pragma unroll
      for (int kk = 0; kk < 2; ++kk)
#pragma unroll
        for (int nd = 0; nd < 4; ++nd)
          vf[kk][nd] = *reinterpret_cast<const half8*>(
              &Vst[cur][(nd * 16 + lr) * 64 + ((kk * 4 + hi) ^ (lr & 7)) * 8]);
      // ---- scores2 = (Q*QSCALE) K^T (log2-domain) ----
      f32x4 accS[4] = {};
#pragma unroll
      for (int ni = 0; ni < 4; ++ni)
#pragma unroll
        for (int kk = 0; kk < 2; ++kk)
          accS[ni] = __builtin_amdgcn_mfma_f32_16x16x32_f16(qf[kk], kf[ni][kk], accS[ni], 0, 0, 0);
      // ---- causal mask: only the last tile of a phase touches the diagonal ----
      if (kt == nkt - 1) {
#pragma unroll
        for (int ni = 0; ni < 4; ++ni)
#pragma unroll
          for (int j = 0; j < 4; ++j) {
            int colg = k0 + ni * 16 + lr;
            int rowg = qg0 + hi * 4 + j;
            if (colg > rowg) accS[ni][j] = -1e30f;
          }
      }
      // ---- online softmax, exp2 domain ----
      f32x4 rmax = accS[0];
#pragma unroll
      for (int ni = 1; ni < 4; ++ni)
#pragma unroll
        for (int j = 0; j < 4; ++j) rmax[j] = fmaxf(rmax[j], accS[ni][j]);
#pragma unroll
      for (int d = 1; d < 16; d <<= 1)
#pragma unroll
        for (int j = 0; j < 4; ++j) rmax[j] = fmaxf(rmax[j], __shfl_xor(rmax[j], d));
      f32x4 mnew, corr;
#pragma unroll
      for (int j = 0; j < 4; ++j) {
        mnew[j] = fmaxf(mrun[j], rmax[j]);
        corr[j] = exp2f(mrun[j] - mnew[j]);
        mrun[j] = mnew[j];
      }
      f32x4 rsum = {};
#pragma unroll
      for (int ni = 0; ni < 4; ++ni)
#pragma unroll
        for (int j = 0; j < 4; ++j) {
          float pv = exp2f(accS[ni][j] - mnew[j]);
          rsum[j] += pv;
          P[hi * 4 + j][ni * 16 + lr] = (_Float16)pv;
        }
#pragma unroll
      for (int d = 1; d < 16; d <<= 1)
#pragma unroll
        for (int j = 0; j < 4; ++j) rsum[j] += __shfl_xor(rsum[j], d);
#pragma unroll
      for (int j = 0; j < 4; ++j) lrun[j] = lrun[j] * corr[j] + rsum[j];
#pragma unroll
      for (int nd = 0; nd < 4; ++nd)
#pragma unroll
        for (int j = 0; j < 4; ++j) accO[nd][j] *= corr[j];
      // ---- PV: O += P @ V ----
#pragma unroll
      for (int kk = 0; kk < 2; ++kk) {
        half8 pa = *reinterpret_cast<const half8*>(&P[lr][kk * 32 + hi * 8]);
#pragma unroll
        for (int nd = 0; nd < 4; ++nd)
          accO[nd] = __builtin_amdgcn_mfma_f32_16x16x32_f16(pa, vf[kk][nd], accO[nd], 0, 0, 0);
      }
      asm volatile("s_barrier" ::: "memory");  // all waves done reading buf[cur]
    }
    // ---- epilogue: AO[b, s, h*64+d] = O / l ----
    f32x4 inv;
#pragma unroll
    for (int j = 0; j < 4; ++j) inv[j] = 1.0f / lrun[j];
#pragma unroll
    for (int nd = 0; nd < 4; ++nd)
#pragma unroll
      for (int j = 0; j < 4; ++j) {
        int s = qg0 + hi * 4 + j;
        int d = nd * 16 + lr;
        AO[(size_t)(b * 2048 + s) * 1024 + h * 64 + d] = (_Float16)(accO[nd][j] * inv[j]);
      }
  };

  PHASE(p * 64, p + 1);            // light tile: keys [0, 64(p+1))
  PHASE((31 - p) * 64, 32 - p);    // heavy tile: keys [0, 64(32-p))  -> 33 total
}

extern "C" void kernel_launch(void* const* d_in, const int* in_sizes, int n_in,
                              void* d_out, int out_size, void* d_ws, size_t ws_size,
                              hipStream_t stream) {
  const float* x = (const float*)d_in[0];      // [2,2048,1024]
  const float* wqkv = (const float*)d_in[1];   // [3072,1024]
  const float* wout = (const float*)d_in[2];   // [1024,1024]
  float* out = (float*)d_out;                  // [2,2048,1024] fp32
  char* ws = (char*)d_ws;
  _Float16* xh  = (_Float16*)(ws + (size_t)0);          // 8 MB
  _Float16* wqh = (_Float16*)(ws + ((size_t)8 << 20));  // 6 MB
  _Float16* woh = (_Float16*)(ws + ((size_t)14 << 20)); // 2 MB
  _Float16* Qb  = (_Float16*)(ws + ((size_t)16 << 20)); // 8 MB [b,h,s,d] pre-scaled
  _Float16* Kb  = (_Float16*)(ws + ((size_t)24 << 20)); // 8 MB [b,h,s,d]
  _Float16* Vtb = (_Float16*)(ws + ((size_t)32 << 20)); // 8 MB [b,h,d,s]
  _Float16* AOb = (_Float16*)(ws + ((size_t)40 << 20)); // 8 MB [b,s,h*64+d]

  cast_all_f16<<<dim3(4096), 256, 0, stream>>>(x, wqkv, wout, xh, wqh, woh);
  gemm_qkv<<<dim3(24, 32), 256, 0, stream>>>(xh, wqh, Qb, Kb, Vtb);
  attn_f16<<<dim3(512), 256, 0, stream>>>(Qb, Kb, Vtb, AOb);
  gemm_out64<<<dim3(8, 64), 256, 0, stream>>>(AOb, woh, out);
}

// Round 11
// 184.679 us; speedup vs baseline: 1.9447x; 1.1107x over previous
//
#include <hip/hip_runtime.h>
#include <hip/hip_fp16.h>

// SimpleAttention on MI355X (gfx950), f16 MFMA path with fp32 accum.
// Pipeline: cast(x,wqkv,wout) -> QKV GEMM -> causal flash attn -> out GEMM.
// R10 = R8 with P-pack via plain scalar casts (m240: compiler fuses to cvt_pk;
// avoids the builtin whose return type broke R9's compile).
// R8 attn: swapped-operand QK^T (scores lane-local per q-row) -> in-lane
// softmax (2 shfls), scalar corr/exp2, packed P/O stores; s_setprio on MFMA.

typedef _Float16 half8 __attribute__((ext_vector_type(8)));
typedef _Float16 half4 __attribute__((ext_vector_type(4)));
typedef float f32x4 __attribute__((ext_vector_type(4)));

typedef const __attribute__((address_space(1))) void gvoid_t;
typedef __attribute__((address_space(3))) void lvoid_t;

#define LOG2E 1.4426950408889634f
#define QSCALE (0.125f * LOG2E)

// ---------------- fused fp32 -> fp16 cast, 8 elems/thread ----------------
__global__ void cast_all_f16(const float* __restrict__ x, const float* __restrict__ wq,
                             const float* __restrict__ wo, _Float16* __restrict__ xh,
                             _Float16* __restrict__ wqh, _Float16* __restrict__ woh) {
  int i = blockIdx.x * blockDim.x + threadIdx.x;
  const float* src;
  _Float16* dst;
  int off;
  if (i < 524288) { src = x; dst = xh; off = i; }
  else if (i < 917504) { src = wq; dst = wqh; off = i - 524288; }
  else { src = wo; dst = woh; off = i - 917504; }
  const float4* p = reinterpret_cast<const float4*>(src) + (size_t)off * 2;
  float4 a = p[0], b = p[1];
  half8 h;
  h[0] = (_Float16)a.x; h[1] = (_Float16)a.y; h[2] = (_Float16)a.z; h[3] = (_Float16)a.w;
  h[4] = (_Float16)b.x; h[5] = (_Float16)b.y; h[6] = (_Float16)b.z; h[7] = (_Float16)b.w;
  reinterpret_cast<half8*>(dst)[off] = h;
}

// ---------------- QKV GEMM: C[M,N] = A[M,K] * B[N,K]^T, K=1024 ----------------
__global__ __launch_bounds__(256) void gemm_qkv(
    const _Float16* __restrict__ A, const _Float16* __restrict__ B,
    _Float16* __restrict__ Qo, _Float16* __restrict__ Ko, _Float16* __restrict__ Vto)
{
  __shared__ __align__(16) _Float16 As[128 * 32];
  __shared__ __align__(16) _Float16 Bs[128 * 32];
  const int tid = threadIdx.x;
  const int lane = tid & 63;
  const int w = tid >> 6;
  const int lr = lane & 15, hi = lane >> 4;
  const int wr = w >> 1, wc = w & 1;
  const int gm = blockIdx.y, gn = blockIdx.x;
  const _Float16* gA = A + (size_t)gm * 128 * 1024;
  const _Float16* gB = B + (size_t)gn * 128 * 1024;
  f32x4 acc[4][4] = {};

#define STAGE2(gp, sp)                                                                  \
  { _Pragma("unroll") for (int i_ = 0; i_ < 2; ++i_) {                                  \
      int c_ = i_ * 256 + tid; int r_ = c_ >> 2; int ko_ = (c_ & 3) * 8;                \
      __builtin_amdgcn_global_load_lds((gvoid_t*)((gp) + r_ * 1024 + ko_),              \
                                       (lvoid_t*)((sp) + c_ * 8), 16, 0, 0);            \
    } }

  STAGE2(gA, As)
  STAGE2(gB, Bs)
  for (int ks = 0;; ++ks) {
    __syncthreads();
    half8 af[4], bf[4];
#pragma unroll
    for (int mi = 0; mi < 4; ++mi)
      af[mi] = *reinterpret_cast<const half8*>(As + (wr * 64 + mi * 16 + lr) * 32 + hi * 8);
#pragma unroll
    for (int ni = 0; ni < 4; ++ni)
      bf[ni] = *reinterpret_cast<const half8*>(Bs + (wc * 64 + ni * 16 + lr) * 32 + hi * 8);
#pragma unroll
    for (int mi = 0; mi < 4; ++mi)
#pragma unroll
      for (int ni = 0; ni < 4; ++ni)
        acc[mi][ni] = __builtin_amdgcn_mfma_f32_16x16x32_f16(af[mi], bf[ni], acc[mi][ni], 0, 0, 0);
    if (ks == 31) break;
    __syncthreads();
    STAGE2(gA + (ks + 1) * 32, As)
    STAGE2(gB + (ks + 1) * 32, Bs)
  }

  const int row0 = gm * 128 + wr * 64;
  const int col0 = gn * 128 + wc * 64;
#pragma unroll
  for (int ni = 0; ni < 4; ++ni) {
    int col = col0 + ni * 16 + lr;          // 0..3071
    int t = col >> 10, h = (col >> 6) & 15, d = col & 63;
#pragma unroll
    for (int mi = 0; mi < 4; ++mi) {
      int row = row0 + mi * 16 + hi * 4;    // j=0 row; j stays within same b
      int b = row >> 11, s = row & 2047;
      if (t == 2) {
        half4 pk = { (_Float16)acc[mi][ni][0], (_Float16)acc[mi][ni][1],
                     (_Float16)acc[mi][ni][2], (_Float16)acc[mi][ni][3] };
        *reinterpret_cast<half4*>(Vto + ((size_t)(b * 16 + h) * 64 + d) * 2048 + s) = pk;
      } else if (t == 0) {
#pragma unroll
        for (int j = 0; j < 4; ++j)
          Qo[(size_t)((b * 16 + h) * 2048 + s + j) * 64 + d] =
              (_Float16)(acc[mi][ni][j] * QSCALE);
      } else {
#pragma unroll
        for (int j = 0; j < 4; ++j)
          Ko[(size_t)((b * 16 + h) * 2048 + s + j) * 64 + d] = (_Float16)acc[mi][ni][j];
      }
    }
  }
}

// ---------------- out GEMM: Co[4096,1024] = A[4096,K]*B[1024,K]^T ----------------
__global__ __launch_bounds__(256) void gemm_out64(
    const _Float16* __restrict__ A, const _Float16* __restrict__ B,
    float* __restrict__ Co)
{
  __shared__ __align__(16) _Float16 As[64 * 32];
  __shared__ __align__(16) _Float16 Bs[128 * 32];
  const int tid = threadIdx.x;
  const int lane = tid & 63;
  const int w = tid >> 6;
  const int lr = lane & 15, hi = lane >> 4;
  const int gm = blockIdx.y, gn = blockIdx.x;
  const _Float16* gA = A + (size_t)gm * 64 * 1024;
  const _Float16* gB = B + (size_t)gn * 128 * 1024;
  f32x4 acc[4][2] = {};

#define STAGEA(gp)                                                                      \
  { int r_ = tid >> 2; int ko_ = (tid & 3) * 8;                                         \
    __builtin_amdgcn_global_load_lds((gvoid_t*)((gp) + r_ * 1024 + ko_),                \
                                     (lvoid_t*)(As + tid * 8), 16, 0, 0); }

  STAGEA(gA)
  STAGE2(gB, Bs)
  for (int ks = 0;; ++ks) {
    __syncthreads();
    half8 af[4], bf[2];
#pragma unroll
    for (int mi = 0; mi < 4; ++mi)
      af[mi] = *reinterpret_cast<const half8*>(As + (mi * 16 + lr) * 32 + hi * 8);
#pragma unroll
    for (int ni = 0; ni < 2; ++ni)
      bf[ni] = *reinterpret_cast<const half8*>(Bs + (w * 32 + ni * 16 + lr) * 32 + hi * 8);
#pragma unroll
    for (int mi = 0; mi < 4; ++mi)
#pragma unroll
      for (int ni = 0; ni < 2; ++ni)
        acc[mi][ni] = __builtin_amdgcn_mfma_f32_16x16x32_f16(af[mi], bf[ni], acc[mi][ni], 0, 0, 0);
    if (ks == 31) break;
    __syncthreads();
    STAGEA(gA + (ks + 1) * 32)
    STAGE2(gB + (ks + 1) * 32, Bs)
  }
#undef STAGEA
#undef STAGE2

#pragma unroll
  for (int mi = 0; mi < 4; ++mi)
#pragma unroll
    for (int j = 0; j < 4; ++j) {
      int row = gm * 64 + mi * 16 + hi * 4 + j;
#pragma unroll
      for (int ni = 0; ni < 2; ++ni) {
        int col = gn * 128 + w * 32 + ni * 16 + lr;
        Co[(size_t)row * 1024 + col] = acc[mi][ni][j];
      }
    }
}

// ---------------- causal flash attention (swapped QK^T) ----------------
// 512 blocks. Block -> (pair p, bh) via XCD-chunked swizzle. Block does q-tile p
// then q-tile 31-p: uniform 33 key-tiles. 4 waves x 16 q-rows. K/V staged to LDS
// (double-buffered, swizzled source). Swapped QK^T: lane holds all 64 key scores
// of q-row (lane&15) -> in-lane softmax, 2 shfls, scalar corr.
__global__ __launch_bounds__(256, 2) void attn_f16(
    const _Float16* __restrict__ Qg, const _Float16* __restrict__ Kg,
    const _Float16* __restrict__ Vtg, _Float16* __restrict__ AO)
{
  const int bid = blockIdx.x;
  const int virt = ((bid & 7) << 6) | (bid >> 3);  // 512 = 8 XCDs x 64-chunk, bijective
  const int p = virt & 15;
  const int bh = virt >> 4;
  const int tid = threadIdx.x;
  const int w = tid >> 6, lane = tid & 63;
  const int lr = lane & 15, hi = lane >> 4;
  const _Float16* Qh = Qg + (size_t)bh * 2048 * 64;
  const _Float16* Kh = Kg + (size_t)bh * 2048 * 64;
  const _Float16* Vh = Vtg + (size_t)bh * 64 * 2048;  // [d][s]
  const int b = bh >> 4, h = bh & 15;

  __shared__ __align__(16) _Float16 Kst[2][64 * 64];  // 8KB x2, swizzled slots
  __shared__ __align__(16) _Float16 Vst[2][64 * 64];  // 8KB x2
  __shared__ __align__(16) _Float16 Plds[4][16][72];  // per-wave P[q][key], stride 72
  _Float16(*P)[72] = Plds[w];

  auto STAGE = [&](int buf, int kt) {
    const int k0 = kt * 64;
#pragma unroll
    for (int i = 0; i < 2; ++i) {
      int f = i * 256 + tid, r = f >> 3, s = f & 7, ss = s ^ (r & 7);
      __builtin_amdgcn_global_load_lds((gvoid_t*)(Kh + (size_t)(k0 + r) * 64 + ss * 8),
                                       (lvoid_t*)(&Kst[buf][f * 8]), 16, 0, 0);
    }
#pragma unroll
    for (int i = 0; i < 2; ++i) {
      int f = i * 256 + tid, r = f >> 3, s = f & 7, ss = s ^ (r & 7);
      __builtin_amdgcn_global_load_lds((gvoid_t*)(Vh + (size_t)r * 2048 + k0 + ss * 8),
                                       (lvoid_t*)(&Vst[buf][f * 8]), 16, 0, 0);
    }
  };

  auto PHASE = [&](int q0, int nkt) {
    const int qg0 = q0 + w * 16;
    half8 qf[2];
#pragma unroll
    for (int kk = 0; kk < 2; ++kk)
      qf[kk] = *reinterpret_cast<const half8*>(Qh + (size_t)(qg0 + lr) * 64 + kk * 32 + hi * 8);
    f32x4 accO[4] = {};
    float mrun = -1e30f, lrun = 0.f;

    asm volatile("s_barrier" ::: "memory");  // all waves done with prev phase's bufs
    STAGE(0, 0);
    for (int kt = 0; kt < nkt; ++kt) {
      const int k0 = kt * 64;
      const int cur = kt & 1;
      if (kt + 1 < nkt) {
        STAGE(cur ^ 1, kt + 1);
        asm volatile("s_waitcnt vmcnt(4)" ::: "memory");  // current tile's 4 loads done
      } else {
        asm volatile("s_waitcnt vmcnt(0)" ::: "memory");
      }
      __builtin_amdgcn_sched_barrier(0);
      asm volatile("s_barrier" ::: "memory");  // buf[cur] ready for all waves
      // ---- fragments from LDS (swizzled read) ----
      half8 kf[4][2], vf[2][4];
#pragma unroll
      for (int ni = 0; ni < 4; ++ni)
#pragma unroll
        for (int kk = 0; kk < 2; ++kk)
          kf[ni][kk] = *reinterpret_cast<const half8*>(
              &Kst[cur][(ni * 16 + lr) * 64 + ((kk * 4 + hi) ^ (lr & 7)) * 8]);
#pragma unroll
      for (int kk = 0; kk < 2; ++kk)
#pragma unroll
        for (int nd = 0; nd < 4; ++nd)
          vf[kk][nd] = *reinterpret_cast<const half8*>(
              &Vst[cur][(nd * 16 + lr) * 64 + ((kk * 4 + hi) ^ (lr & 7)) * 8]);
      // ---- scores^T = K (Q*QSCALE)^T : lane holds q=lr, keys ni*16+hi*4+j ----
      f32x4 accS[4] = {};
      __builtin_amdgcn_s_setprio(1);
#pragma unroll
      for (int ni = 0; ni < 4; ++ni)
#pragma unroll
        for (int kk = 0; kk < 2; ++kk)
          accS[ni] = __builtin_amdgcn_mfma_f32_16x16x32_f16(kf[ni][kk], qf[kk], accS[ni], 0, 0, 0);
      __builtin_amdgcn_s_setprio(0);
      // ---- causal mask (last tile of phase only) ----
      if (kt == nkt - 1) {
        const int rowg = qg0 + lr;
#pragma unroll
        for (int ni = 0; ni < 4; ++ni)
#pragma unroll
          for (int j = 0; j < 4; ++j) {
            int keyg = k0 + ni * 16 + hi * 4 + j;
            if (keyg > rowg) accS[ni][j] = -1e30f;
          }
      }
      // ---- online softmax, exp2 domain, per-lane row ----
      f32x4 m4 = accS[0];
#pragma unroll
      for (int ni = 1; ni < 4; ++ni)
#pragma unroll
        for (int j = 0; j < 4; ++j) m4[j] = fmaxf(m4[j], accS[ni][j]);
      float rm = fmaxf(fmaxf(m4[0], m4[1]), fmaxf(m4[2], m4[3]));
      rm = fmaxf(rm, __shfl_xor(rm, 16));
      rm = fmaxf(rm, __shfl_xor(rm, 32));
      const float mnew = fmaxf(mrun, rm);
      const float corr = exp2f(mrun - mnew);
      mrun = mnew;
#pragma unroll
      for (int ni = 0; ni < 4; ++ni)
#pragma unroll
        for (int j = 0; j < 4; ++j) accS[ni][j] = exp2f(accS[ni][j] - mnew);
      f32x4 s4 = accS[0];
#pragma unroll
      for (int ni = 1; ni < 4; ++ni)
#pragma unroll
        for (int j = 0; j < 4; ++j) s4[j] += accS[ni][j];
      float rs = (s4[0] + s4[1]) + (s4[2] + s4[3]);
      rs += __shfl_xor(rs, 16);
      rs += __shfl_xor(rs, 32);
      lrun = lrun * corr + rs;
#pragma unroll
      for (int nd = 0; nd < 4; ++nd)
#pragma unroll
        for (int j = 0; j < 4; ++j) accO[nd][j] *= corr;
      // ---- P pack (scalar casts; compiler fuses to cvt_pk) -> LDS [q=lr][key] ----
#pragma unroll
      for (int ni = 0; ni < 4; ++ni) {
        half4 pk = { (_Float16)accS[ni][0], (_Float16)accS[ni][1],
                     (_Float16)accS[ni][2], (_Float16)accS[ni][3] };
        *reinterpret_cast<half4*>(&P[lr][ni * 16 + hi * 4]) = pk;
      }
      // ---- PV: O^T = V^T P^T -> lane holds O[q=lr][d=nd*16+hi*4+j] ----
      __builtin_amdgcn_s_setprio(1);
#pragma unroll
      for (int kk = 0; kk < 2; ++kk) {
        half8 pb = *reinterpret_cast<const half8*>(&P[lr][kk * 32 + hi * 8]);
#pragma unroll
        for (int nd = 0; nd < 4; ++nd)
          accO[nd] = __builtin_amdgcn_mfma_f32_16x16x32_f16(vf[kk][nd], pb, accO[nd], 0, 0, 0);
      }
      __builtin_amdgcn_s_setprio(0);
      asm volatile("s_barrier" ::: "memory");  // all waves done reading buf[cur]
    }
    // ---- epilogue: AO[b, s=qg0+lr, h*64+d] = O / l  (4x 8B packed stores) ----
    const float inv = 1.0f / lrun;
    const size_t base = (size_t)(b * 2048 + qg0 + lr) * 1024 + h * 64;
#pragma unroll
    for (int nd = 0; nd < 4; ++nd) {
      half4 ov = { (_Float16)(accO[nd][0] * inv), (_Float16)(accO[nd][1] * inv),
                   (_Float16)(accO[nd][2] * inv), (_Float16)(accO[nd][3] * inv) };
      *reinterpret_cast<half4*>(AO + base + nd * 16 + hi * 4) = ov;
    }
  };

  PHASE(p * 64, p + 1);            // light tile: keys [0, 64(p+1))
  PHASE((31 - p) * 64, 32 - p);    // heavy tile: keys [0, 64(32-p))  -> 33 total
}

extern "C" void kernel_launch(void* const* d_in, const int* in_sizes, int n_in,
                              void* d_out, int out_size, void* d_ws, size_t ws_size,
                              hipStream_t stream) {
  const float* x = (const float*)d_in[0];      // [2,2048,1024]
  const float* wqkv = (const float*)d_in[1];   // [3072,1024]
  const float* wout = (const float*)d_in[2];   // [1024,1024]
  float* out = (float*)d_out;                  // [2,2048,1024] fp32
  char* ws = (char*)d_ws;
  _Float16* xh  = (_Float16*)(ws + (size_t)0);          // 8 MB
  _Float16* wqh = (_Float16*)(ws + ((size_t)8 << 20));  // 6 MB
  _Float16* woh = (_Float16*)(ws + ((size_t)14 << 20)); // 2 MB
  _Float16* Qb  = (_Float16*)(ws + ((size_t)16 << 20)); // 8 MB [b,h,s,d] pre-scaled
  _Float16* Kb  = (_Float16*)(ws + ((size_t)24 << 20)); // 8 MB [b,h,s,d]
  _Float16* Vtb = (_Float16*)(ws + ((size_t)32 << 20)); // 8 MB [b,h,d,s]
  _Float16* AOb = (_Float16*)(ws + ((size_t)40 << 20)); // 8 MB [b,s,h*64+d]

  cast_all_f16<<<dim3(4096), 256, 0, stream>>>(x, wqkv, wout, xh, wqh, woh);
  gemm_qkv<<<dim3(24, 32), 256, 0, stream>>>(xh, wqh, Qb, Kb, Vtb);
  attn_f16<<<dim3(512), 256, 0, stream>>>(Qb, Kb, Vtb, AOb);
  gemm_out64<<<dim3(8, 64), 256, 0, stream>>>(AOb, woh, out);
}